// Round 11
// baseline (139.228 us; speedup 1.0000x reference)
//
#include <hip/hip_runtime.h>
#include <hip/hip_bf16.h>

#define B_ 4
#define S_ 512
#define E_ 512
#define U_ 256

// 2*log2(e): folded so tanh args feed exp2 directly: exp(2x) = exp2(KC*x)
#define KC 2.885390081777927f

#if __has_builtin(__builtin_amdgcn_exp2f)
#define EXP2F(x) __builtin_amdgcn_exp2f(x)
#else
#define EXP2F(x) __exp2f(x)
#endif
#if __has_builtin(__builtin_amdgcn_rcpf)
#define RCPF(x) __builtin_amdgcn_rcpf(x)
#else
#define RCPF(x) (1.0f / (x))
#endif

typedef __attribute__((ext_vector_type(8))) short bf16x8;
typedef __attribute__((ext_vector_type(4))) float f32x4;

__device__ __forceinline__ unsigned short bf16rn(float x) {
    unsigned int u = __float_as_uint(x);
    u = (u + 0x7FFFu + ((u >> 16) & 1u)) >> 16;   // RNE
    return (unsigned short)u;
}
// truncation split: x = hi + lo (lo exact in fp32); dropped lo*lo term ~2^-16
__device__ __forceinline__ void splitT(float x, short* hi, short* lo) {
    const unsigned u = __float_as_uint(x);
    *hi = (short)(u >> 16);
    const float hf = __uint_as_float(u & 0xFFFF0000u);
    *lo = (short)(__float_as_uint(x - hf) >> 16);
}

// ---------------------------------------------------------------------------
// Kernel 1 (dual role, 1536 blocks x 256 thr):
//  blocks 0..1023 — pre-GEMMs. block <-> (z, ng 0..15 = 16-u slab, mq 0..31).
//    LDS now 32 KB (was 64) -> 4 blocks/CU, 4096 MFMA waves (2x TLP for the
//    latency-exposed A loads). 4 waves convert the W slab into LDS B-frag
//    hi/lo, then each wave computes one 16-row m-tile (16r x 16u).
//      z==0: keySt[b][u][j] = KC*(h1[b,j,:] @ w1[:,u])    (j contiguous)
//      z==1: qryS [b][i][u] = KC*(h2[b,i,:] @ w2[:,u] + b1[u])
//  blocks 1024..1535 — cast h1 -> h1c in MFMA B-frag order (for pv).
// ---------------------------------------------------------------------------
__global__ __launch_bounds__(256) void prep_gemm(
    const float* __restrict__ h1, const float* __restrict__ h2,
    const float* __restrict__ w, const float* __restrict__ b1,
    float* __restrict__ keySt, float* __restrict__ qryS,
    bf16x8* __restrict__ h1c)
{
    __shared__ unsigned short WhiL[16][64][8];   // [kc][lane][j] 16 KB
    __shared__ unsigned short WloL[16][64][8];   // 16 KB

    const int tid = threadIdx.x;
    const int bid = blockIdx.x;

    if (bid < 1024) {
        const int z = bid >> 9, ng = (bid >> 5) & 15, mq = bid & 31;

        // ---- W slab conversion: 16 u-lanes x 16 k-rows per iteration ----
        const int l16c = tid & 15, r16 = tid >> 4;
        const float* __restrict__ Wp = w + (size_t)z * E_ * U_ + ng * 16 + l16c;
#pragma unroll 4
        for (int it = 0; it < 32; ++it) {
            const int k = it * 16 + r16;
            short h, l;
            splitT(Wp[(size_t)k * U_] * KC, &h, &l);
            const int kc = k >> 5, quad = (k >> 3) & 3, jj = k & 7;
            WhiL[kc][quad * 16 + l16c][jj] = (unsigned short)h;
            WloL[kc][quad * 16 + l16c][jj] = (unsigned short)l;
        }
        __syncthreads();

        // ---- MFMA main loop: one 16-row x 16-u tile per wave ----
        const int wv = tid >> 6, lane = tid & 63;
        const int quad = lane >> 4, l16 = lane & 15;
        const int m0 = (mq * 4 + wv) * 16;
        const float* __restrict__ Arow = (z ? h2 : h1) + (size_t)(m0 + l16) * E_;

        f32x4 acc = (f32x4){0.f, 0.f, 0.f, 0.f};

        for (int kc = 0; kc < 16; ++kc) {
            const int kb = kc * 32 + quad * 8;
            const float4 x0 = *(const float4*)&Arow[kb];
            const float4 x1 = *(const float4*)&Arow[kb + 4];
            const float xs[8] = {x0.x, x0.y, x0.z, x0.w, x1.x, x1.y, x1.z, x1.w};
            bf16x8 ah, al;
#pragma unroll
            for (int j = 0; j < 8; ++j) {
                short h, l; splitT(xs[j], &h, &l);
                ah[j] = h; al[j] = l;
            }
            const bf16x8 bh = *(const bf16x8*)&WhiL[kc][lane][0];
            const bf16x8 bl = *(const bf16x8*)&WloL[kc][lane][0];
            acc = __builtin_amdgcn_mfma_f32_16x16x32_bf16(ah, bh, acc, 0, 0, 0);
            acc = __builtin_amdgcn_mfma_f32_16x16x32_bf16(ah, bl, acc, 0, 0, 0);
            acc = __builtin_amdgcn_mfma_f32_16x16x32_bf16(al, bh, acc, 0, 0, 0);
        }

        const int u = ng * 16 + l16;                     // C/D col = u
        if (z == 0) {
            const int b = m0 >> 9;
            const int j0 = (m0 & (S_ - 1)) + quad * 4;   // C/D row = j
            *(float4*)&keySt[((size_t)b * U_ + u) * S_ + j0] =
                make_float4(acc[0], acc[1], acc[2], acc[3]);
        } else {
            const int row = m0 + quad * 4;
            const float bias = KC * b1[u];
#pragma unroll
            for (int r = 0; r < 4; ++r)
                qryS[(size_t)(row + r) * U_ + u] = acc[r] + bias;
        }
    } else {
        // ---- h1 -> bf16 B-frag cast for pv ----
        const int s = (bid - 1024) * 256 + tid;
        const int lane = s & 63, kc = (s >> 6) & 15, et = (s >> 10) & 31, b = s >> 15;
        const int quad = lane >> 4, l16 = lane & 15;
        const float* __restrict__ src =
            h1 + ((size_t)b * S_ + kc * 32 + quad * 8) * E_ + et * 16 + l16;
        bf16x8 c;
#pragma unroll
        for (int j = 0; j < 8; ++j)
            c[j] = (short)bf16rn(src[(size_t)j * E_]);
        h1c[s] = c;
    }
}

// ---------------------------------------------------------------------------
// scores + softmax -> P packed in MFMA A-frag order (bf16).
// TI=4: 512 thr/block, thread t <-> column j = t, grid (128,4) = 512 blocks
// = 2 blocks/CU, 16 waves/CU. Register-prefetch of the next 4 k-rows before
// computing the current quadTerms (R10 was ~85% issue-bound; the rest was
// k-load latency gaps — overlap them).
// a = sum_u v_u/(exp2(arg)+1); score = c - 2a (c, b2 cancel) ->
// p ~ exp2(-a*KC); |a*KC| <= ~52 so no max-shift needed.
// ---------------------------------------------------------------------------
__device__ __forceinline__ float quadTerm(float a0, float a1, float a2, float a3,
                                          float4 vq, float acc) {
    const float F1 = EXP2F(a0) + 1.f;
    const float F2 = EXP2F(a1) + 1.f;
    const float F3 = EXP2F(a2) + 1.f;
    const float F4 = EXP2F(a3) + 1.f;
    const float P12 = F1 * F2, P34 = F3 * F4;
    const float n12 = fmaf(vq.y, F1, vq.x * F2);
    const float n34 = fmaf(vq.w, F3, vq.z * F4);
    const float num = fmaf(n34, P12, n12 * P34);
    return fmaf(num, RCPF(P12 * P34), acc);
}

__global__ __launch_bounds__(512) void scores_kernel(
    const float* __restrict__ keySt, const float* __restrict__ qryS,
    const float* __restrict__ v, unsigned short* __restrict__ Pp)
{
    const int i0 = blockIdx.x * 4;
    const int b = blockIdx.y;
    const int t = threadIdx.x;          // j = t
    const int wv = t >> 6;

    __shared__ float ssm[8][4];

    const float4* __restrict__ q0v = (const float4*)(qryS + ((size_t)b * S_ + i0) * U_);
    const float4* __restrict__ q1v = q0v + (U_ / 4);
    const float4* __restrict__ q2v = q0v + 2 * (U_ / 4);
    const float4* __restrict__ q3v = q0v + 3 * (U_ / 4);
    const float4* __restrict__ vv4 = (const float4*)v;
    const float* __restrict__ kp = keySt + (size_t)b * U_ * S_ + t;

    float a0 = 0.f, a1 = 0.f, a2 = 0.f, a3 = 0.f;
    float k0 = kp[0], k1 = kp[S_], k2 = kp[2 * S_], k3 = kp[3 * S_];
    kp += 4 * S_;
#pragma unroll 4
    for (int ub = 0; ub < U_ / 4 - 1; ++ub) {
        const float n0 = kp[0], n1 = kp[S_], n2 = kp[2 * S_], n3 = kp[3 * S_];
        kp += 4 * S_;
        const float4 vq = vv4[ub];                     // uniform -> SGPR
        const float4 q0 = q0v[ub], q1 = q1v[ub], q2 = q2v[ub], q3 = q3v[ub];
        a0 = quadTerm(q0.x + k0, q0.y + k1, q0.z + k2, q0.w + k3, vq, a0);
        a1 = quadTerm(q1.x + k0, q1.y + k1, q1.z + k2, q1.w + k3, vq, a1);
        a2 = quadTerm(q2.x + k0, q2.y + k1, q2.z + k2, q2.w + k3, vq, a2);
        a3 = quadTerm(q3.x + k0, q3.y + k1, q3.z + k2, q3.w + k3, vq, a3);
        k0 = n0; k1 = n1; k2 = n2; k3 = n3;
    }
    {
        const int ub = U_ / 4 - 1;
        const float4 vq = vv4[ub];
        const float4 q0 = q0v[ub], q1 = q1v[ub], q2 = q2v[ub], q3 = q3v[ub];
        a0 = quadTerm(q0.x + k0, q0.y + k1, q0.z + k2, q0.w + k3, vq, a0);
        a1 = quadTerm(q1.x + k0, q1.y + k1, q1.z + k2, q1.w + k3, vq, a1);
        a2 = quadTerm(q2.x + k0, q2.y + k1, q2.z + k2, q2.w + k3, vq, a2);
        a3 = quadTerm(q3.x + k0, q3.y + k1, q3.z + k2, q3.w + k3, vq, a3);
    }

    const float p0 = EXP2F(-a0 * KC);
    const float p1 = EXP2F(-a1 * KC);
    const float p2 = EXP2F(-a2 * KC);
    const float p3 = EXP2F(-a3 * KC);
    float s0 = p0, s1 = p1, s2 = p2, s3 = p3;
#pragma unroll
    for (int off = 1; off < 64; off <<= 1) {
        s0 += __shfl_xor(s0, off, 64);
        s1 += __shfl_xor(s1, off, 64);
        s2 += __shfl_xor(s2, off, 64);
        s3 += __shfl_xor(s3, off, 64);
    }
    if ((t & 63) == 0) {
        ssm[wv][0] = s0; ssm[wv][1] = s1; ssm[wv][2] = s2; ssm[wv][3] = s3;
    }
    __syncthreads();
    s0 = ssm[0][0]; s1 = ssm[0][1]; s2 = ssm[0][2]; s3 = ssm[0][3];
#pragma unroll
    for (int k = 1; k < 8; ++k) {
        s0 += ssm[k][0]; s1 += ssm[k][1]; s2 += ssm[k][2]; s3 += ssm[k][3];
    }
    const float r0 = RCPF(s0), r1 = RCPF(s1), r2 = RCPF(s2), r3 = RCPF(s3);

    // pack into A-frag order: slot = (it*16 + j/32)*64 + quad(j)*16 + (i&15),
    // halfword j&7. i0 = 4*blockIdx.x -> rows stay inside one 16-block.
    const int itile = i0 >> 4;
    const int base = (itile * 16 + (t >> 5)) * 64 + (((t >> 3) & 3) << 4);
    unsigned short* __restrict__ pb = Pp + (size_t)b * S_ * S_;
    const int io = i0 & 15, jo = t & 7;
    pb[((base + io + 0) << 3) + jo] = bf16rn(p0 * r0);
    pb[((base + io + 1) << 3) + jo] = bf16rn(p1 * r1);
    pb[((base + io + 2) << 3) + jo] = bf16rn(p2 * r2);
    pb[((base + io + 3) << 3) + jo] = bf16rn(p3 * r3);
}

// ---------------------------------------------------------------------------
// pv: out[b] = P[b] @ h1[b]; A-frags pre-packed by scores, B-frags (h1c)
// by prep_gemm. Wave-task (b, it 0..31, et 0..31): ONE 16i x 16e tile/wave.
// 4096 wave-tasks (grid 1024x256) = 4 waves/SIMD — R10 ran this at 1
// wave/SIMD, fully exposed to the ~600cyc cross-XCD L2 latency of Pp/h1c.
// ---------------------------------------------------------------------------
__global__ __launch_bounds__(256) void pv_gemm(
    const unsigned short* __restrict__ Pp, const bf16x8* __restrict__ h1c,
    float* __restrict__ out)
{
    const int tid = threadIdx.x;
    const int wv = tid >> 6, lane = tid & 63;
    const int quad = lane >> 4, l16 = lane & 15;
    const int wt = blockIdx.x * 4 + wv;
    const int b = wt >> 10, rem = wt & 1023;
    const int it = rem >> 5, et = rem & 31;

    const bf16x8* __restrict__ Ab =
        (const bf16x8*)(Pp + (size_t)b * S_ * S_) + (it * 16) * 64 + lane;
    const bf16x8* __restrict__ Bb =
        h1c + ((b * 32 + et) * 16) * 64 + lane;

    f32x4 acc = (f32x4){0.f, 0.f, 0.f, 0.f};

    for (int kc = 0; kc < 16; ++kc) {
        const bf16x8 a8 = Ab[kc * 64];
        const bf16x8 b8 = Bb[kc * 64];
        acc = __builtin_amdgcn_mfma_f32_16x16x32_bf16(a8, b8, acc, 0, 0, 0);
    }

    const int i = it * 16 + quad * 4;
    const int e = et * 16 + l16;
    float* __restrict__ ob = out + ((size_t)b * S_ + i) * E_ + e;
#pragma unroll
    for (int r = 0; r < 4; ++r)
        ob[(size_t)r * E_] = acc[r];
}

extern "C" void kernel_launch(void* const* d_in, const int* in_sizes, int n_in,
                              void* d_out, int out_size, void* d_ws, size_t ws_size,
                              hipStream_t stream) {
    const float* h1 = (const float*)d_in[0];
    const float* h2 = (const float*)d_in[1];
    const float* w  = (const float*)d_in[2];
    const float* b1 = (const float*)d_in[3];
    const float* v  = (const float*)d_in[4];
    // d_in[5] = b2: cancels in softmax, unused.
    float* out = (float*)d_out;

    char* ws = (char*)d_ws;
    float* keySt = (float*)ws;                 ws += 2u << 20;  // 2 MB
    float* qryS  = (float*)ws;                 ws += 2u << 20;  // 2 MB
    unsigned short* Pp = (unsigned short*)ws;  ws += 2u << 20;  // 2 MB
    bf16x8* h1c = (bf16x8*)ws;                                  // 2 MB

    prep_gemm<<<dim3(1536), dim3(256), 0, stream>>>(h1, h2, w, b1, keySt, qryS, h1c);
    scores_kernel<<<dim3(S_ / 4, B_), dim3(512), 0, stream>>>(keySt, qryS, v, Pp);
    pv_gemm<<<dim3(1024), dim3(256), 0, stream>>>(Pp, h1c, out);
}